// Round 7
// baseline (275.781 us; speedup 1.0000x reference)
//
#include <hip/hip_runtime.h>
#include <hip/hip_bf16.h>
#include <hip/hip_cooperative_groups.h>
#include <math.h>

namespace cg = cooperative_groups;

// Hausdorff distance loss, exact EDT — single cooperative kernel.
// pred  [16, 2, 256, 256] f32 logits; target [16, 256, 256] i32 {0,1}.
// pred_lbl = (pred[:,1] > pred[:,0]); dt = exact 2D EDT of each mask.
// out = (sum(pred_lbl * dt(target)) + sum(target * dt(pred_lbl))) / (2*NPIX)
//
// Phase A (row pass): one wave per row, shuffle cummax scans; stashes both
//   binary masks as uchar labels. 8 rows/block.
// Phase B (col pass): radius-bounded exact min-plus. Candidate y'=y gives
//   upper bound U = g2[y,x]; any y' with (y-y')^2 >= U cannot win (g2 >= 0),
//   so scanning [y0-r, y0+3+r], r = floor(sqrt(U))+1, is exact for ANY input.
//   2 tiles/block, per-block partial (no atomics).
// Phase C: block 0 tree-reduces 1024 partials -> scalar.

#define B 16
#define H 256
#define W 256
#define IMG (H * W)            // 65536
#define NPIX (B * IMG)         // 1048576
#define NEGF (-1.0e6f)
#define NINF (-3.0e38f)
#define GRID 1024

__global__ __launch_bounds__(256, 4) void fused_kernel(
    const float* __restrict__ pred, const int* __restrict__ target,
    float* __restrict__ g2, unsigned char* __restrict__ lbl,
    float* __restrict__ partials, float* __restrict__ out) {
  cg::grid_group grid = cg::this_grid();
  const int tid = threadIdx.x;
  const int lane = tid & 63;
  const int wid = tid >> 6;
  __shared__ float red[256];

  // ---------------- Phase A: row pass (8 rows per block) ----------------
#pragma unroll
  for (int i = 0; i < 2; ++i) {
    const int row = blockIdx.x * 8 + i * 4 + wid;   // [0, 2*B*H)
    const int m = row >> 12;              // 0: pred mask, 1: target mask
    const int bh = row & 4095;
    const int b = bh >> 8;
    const int y = bh & 255;
    const int x0 = lane * 4;

    bool fg[4];
    if (m == 0) {
      const float* base = pred + (size_t)b * (2 * IMG) + y * W + x0;
      const float4 c0 = *(const float4*)(base);
      const float4 c1 = *(const float4*)(base + IMG);
      fg[0] = c1.x > c0.x; fg[1] = c1.y > c0.y;
      fg[2] = c1.z > c0.z; fg[3] = c1.w > c0.w;
    } else {
      const int4 tv = *(const int4*)(target + (size_t)b * IMG + y * W + x0);
      fg[0] = tv.x == 1; fg[1] = tv.y == 1; fg[2] = tv.z == 1; fg[3] = tv.w == 1;
    }

    uchar4 lb;
    lb.x = fg[0]; lb.y = fg[1]; lb.z = fg[2]; lb.w = fg[3];
    *(uchar4*)(lbl + (size_t)m * NPIX + (size_t)b * IMG + y * W + x0) = lb;

    const float xf0 = (float)x0;

    // left-to-right inclusive cummax of pos_l = fg ? x : NEG
    float p0 = fg[0] ? xf0 : NEGF;
    float p1 = fmaxf(p0, fg[1] ? xf0 + 1.f : NEGF);
    float p2 = fmaxf(p1, fg[2] ? xf0 + 2.f : NEGF);
    float p3 = fmaxf(p2, fg[3] ? xf0 + 3.f : NEGF);
    float s = p3;
#pragma unroll
    for (int off = 1; off < 64; off <<= 1) {
      float u = __shfl_up(s, (unsigned)off);
      if (lane >= off) s = fmaxf(s, u);
    }
    float e = __shfl_up(s, 1u);            // exclusive prefix
    if (lane == 0) e = NINF;
    const float dl0 = xf0 - fmaxf(e, p0);
    const float dl1 = xf0 + 1.f - fmaxf(e, p1);
    const float dl2 = xf0 + 2.f - fmaxf(e, p2);
    const float dl3 = xf0 + 3.f - fmaxf(e, p3);

    // right-to-left inclusive cummax of pos_r = fg ? -x : NEG
    float q3 = fg[3] ? -(xf0 + 3.f) : NEGF;
    float q2 = fmaxf(q3, fg[2] ? -(xf0 + 2.f) : NEGF);
    float q1 = fmaxf(q2, fg[1] ? -(xf0 + 1.f) : NEGF);
    float q0 = fmaxf(q1, fg[0] ? -xf0 : NEGF);
    float t = q0;
#pragma unroll
    for (int off = 1; off < 64; off <<= 1) {
      float u = __shfl_down(t, (unsigned)off);
      if (lane < 64 - off) t = fmaxf(t, u);
    }
    float f = __shfl_down(t, 1u);          // exclusive suffix
    if (lane == 63) f = NINF;
    const float dr0 = -fmaxf(f, q0) - xf0;
    const float dr1 = -fmaxf(f, q1) - (xf0 + 1.f);
    const float dr2 = -fmaxf(f, q2) - (xf0 + 2.f);
    const float dr3 = -fmaxf(f, q3) - (xf0 + 3.f);

    float4 o;
    float v;
    v = fminf(dl0, dr0); o.x = v * v;
    v = fminf(dl1, dr1); o.y = v * v;
    v = fminf(dl2, dr2); o.z = v * v;
    v = fminf(dl3, dr3); o.w = v * v;
    *(float4*)(g2 + (size_t)m * NPIX + (size_t)b * IMG + y * W + x0) = o;
  }

  grid.sync();

  // ---------------- Phase B: col pass (2 tiles per block) ----------------
  float local = 0.f;
#pragma unroll
  for (int t2 = 0; t2 < 2; ++t2) {
    const int ti = blockIdx.x + t2 * GRID;   // [0, 2048)
    const int xt = ti & 3;
    const int yt = (ti >> 2) & 15;
    const int m = (ti >> 6) & 1;
    const int b = ti >> 7;
    const int xin = tid & 63;
    const int ysub = tid >> 6;               // 0..3
    const int x = xt * 64 + xin;
    const int y0 = yt * 16 + ysub * 4;

    const float* __restrict__ gimg = g2 + (size_t)m * NPIX + (size_t)b * IMG;

    float a0 = gimg[(y0 + 0) * W + x];
    float a1 = gimg[(y0 + 1) * W + x];
    float a2 = gimg[(y0 + 2) * W + x];
    float a3 = gimg[(y0 + 3) * W + x];

    const float U = fmaxf(fmaxf(a0, a1), fmaxf(a2, a3));
    const int r = (int)sqrtf(U) + 1;   // exact: (y-y')^2 >= U can't improve
    int lo = y0 - r; if (lo < 0) lo = 0;
    int hi = y0 + 3 + r; if (hi > H - 1) hi = H - 1;

    for (int yp = lo; yp <= hi; ++yp) {
      const float v = gimg[yp * W + x];
      const float d0 = (float)(y0 - yp);
      const float d1 = d0 + 1.f;
      const float d2 = d0 + 2.f;
      const float d3 = d0 + 3.f;
      a0 = fminf(a0, fmaf(d0, d0, v));
      a1 = fminf(a1, fmaf(d1, d1, v));
      a2 = fminf(a2, fmaf(d2, d2, v));
      a3 = fminf(a3, fmaf(d3, d3, v));
    }

    // dt = sqrt(dt2), weighted by the OTHER mask's labels
    const unsigned char* wl =
        lbl + (size_t)(1 - m) * NPIX + (size_t)b * IMG + y0 * W + x;
    local += (float)wl[0 * W] * sqrtf(a0);
    local += (float)wl[1 * W] * sqrtf(a1);
    local += (float)wl[2 * W] * sqrtf(a2);
    local += (float)wl[3 * W] * sqrtf(a3);
  }

  red[tid] = local;
  __syncthreads();
  for (int s = 128; s > 0; s >>= 1) {
    if (tid < s) red[tid] += red[tid + s];
    __syncthreads();
  }
  if (tid == 0) partials[blockIdx.x] = red[0];

  grid.sync();

  // ---------------- Phase C: final reduce (block 0) ----------------
  if (blockIdx.x == 0) {
    float s = partials[tid] + partials[tid + 256] +
              partials[tid + 512] + partials[tid + 768];
    red[tid] = s;
    __syncthreads();
    for (int k = 128; k > 0; k >>= 1) {
      if (tid < k) red[tid] += red[tid + k];
      __syncthreads();
    }
    if (tid == 0) out[0] = red[0] * (0.5f / (float)NPIX);
  }
}

// ---------------------------------------------------------------------------
extern "C" void kernel_launch(void* const* d_in, const int* in_sizes, int n_in,
                              void* d_out, int out_size, void* d_ws, size_t ws_size,
                              hipStream_t stream) {
  const float* pred = (const float*)d_in[0];     // [16,2,256,256] f32
  const int* target = (const int*)d_in[1];       // [16,256,256] i32
  float* out = (float*)d_out;                    // scalar f32

  float* g2 = (float*)d_ws;                                // 8 MB
  float* partials = g2 + 2 * (size_t)NPIX;                 // GRID floats
  unsigned char* lbl = (unsigned char*)(partials + GRID);  // 2 MB

  void* args[] = {(void*)&pred, (void*)&target, (void*)&g2,
                  (void*)&lbl, (void*)&partials, (void*)&out};
  hipLaunchCooperativeKernel((void*)fused_kernel, dim3(GRID), dim3(256),
                             args, 0, stream);
}

// Round 8
// 103.035 us; speedup vs baseline: 2.6766x; 2.6766x over previous
//
#include <hip/hip_runtime.h>
#include <hip/hip_bf16.h>
#include <math.h>

// Hausdorff distance loss, exact EDT — block-local fusion (no grid sync).
// pred  [16, 2, 256, 256] f32 logits; target [16, 256, 256] i32 {0,1}.
// pred_lbl = (pred[:,1] > pred[:,0]); dt = exact 2D EDT of each mask.
// out = (sum(pred_lbl * dt(target)) + sum(target * dt(pred_lbl))) / (2*NPIX)
//
// One block = one (m, b, xt) tile: 64 columns x full 256-row height.
// Phase A: all 256 rows' exact 1D scans (full-width wave shuffle cummax;
//   each wave redundantly scans the whole row, stores only the tile's 64
//   columns into LDS). Dependency for the column pass is thus BLOCK-LOCAL
//   -> __syncthreads() instead of the catastrophic grid.sync() (R7: ~90us).
// Phase B: radius-bounded exact column min-plus from LDS. Candidate y'=y
//   gives upper bound U = g2[y,x]; any y' with (y-y')^2 >= U cannot win
//   (g2 >= 0), so scanning [y0-r, y0+3+r], r = floor(sqrt(U))+1 is exact
//   for ANY input. Weight labels for the epilogue are read from global.
// Per-block partial sums; tiny finalize kernel reduces 128 partials.

#define B 16
#define H 256
#define W 256
#define IMG (H * W)            // 65536
#define NPIX (B * IMG)         // 1048576
#define NEGF (-1.0e6f)
#define NINF (-3.0e38f)
#define NBLK 128               // 16 b * 2 m * 4 xt

__global__ __launch_bounds__(512, 2) void edt_fused_kernel(
    const float* __restrict__ pred, const int* __restrict__ target,
    float* __restrict__ partials) {
  __shared__ float g2s[H][64];         // 64 KB: tile's squared 1D distances
  __shared__ float red[512];

  const int tid = threadIdx.x;
  const int lane = tid & 63;
  const int wid = tid >> 6;            // 0..7
  const int bi = blockIdx.x;           // [0, NBLK)
  const int xt = bi & 3;
  const int m = (bi >> 2) & 1;
  const int b = bi >> 3;
  const int x0 = lane * 4;             // this lane's 4 x's in the full row

  // ---------------- Phase A: row pass (32 rows per wave) ----------------
  for (int j = 0; j < 32; ++j) {
    const int y = wid * 32 + j;

    bool fg[4];
    if (m == 0) {
      const float* base = pred + (size_t)b * (2 * IMG) + y * W + x0;
      const float4 c0 = *(const float4*)(base);
      const float4 c1 = *(const float4*)(base + IMG);
      fg[0] = c1.x > c0.x; fg[1] = c1.y > c0.y;
      fg[2] = c1.z > c0.z; fg[3] = c1.w > c0.w;
    } else {
      const int4 tv = *(const int4*)(target + (size_t)b * IMG + y * W + x0);
      fg[0] = tv.x == 1; fg[1] = tv.y == 1; fg[2] = tv.z == 1; fg[3] = tv.w == 1;
    }

    const float xf0 = (float)x0;

    // left-to-right inclusive cummax of pos_l = fg ? x : NEG
    float p0 = fg[0] ? xf0 : NEGF;
    float p1 = fmaxf(p0, fg[1] ? xf0 + 1.f : NEGF);
    float p2 = fmaxf(p1, fg[2] ? xf0 + 2.f : NEGF);
    float p3 = fmaxf(p2, fg[3] ? xf0 + 3.f : NEGF);
    float s = p3;
#pragma unroll
    for (int off = 1; off < 64; off <<= 1) {
      float u = __shfl_up(s, (unsigned)off);
      if (lane >= off) s = fmaxf(s, u);
    }
    float e = __shfl_up(s, 1u);          // exclusive prefix
    if (lane == 0) e = NINF;
    const float dl0 = xf0 - fmaxf(e, p0);
    const float dl1 = xf0 + 1.f - fmaxf(e, p1);
    const float dl2 = xf0 + 2.f - fmaxf(e, p2);
    const float dl3 = xf0 + 3.f - fmaxf(e, p3);

    // right-to-left inclusive cummax of pos_r = fg ? -x : NEG
    float q3 = fg[3] ? -(xf0 + 3.f) : NEGF;
    float q2 = fmaxf(q3, fg[2] ? -(xf0 + 2.f) : NEGF);
    float q1 = fmaxf(q2, fg[1] ? -(xf0 + 1.f) : NEGF);
    float q0 = fmaxf(q1, fg[0] ? -xf0 : NEGF);
    float t = q0;
#pragma unroll
    for (int off = 1; off < 64; off <<= 1) {
      float u = __shfl_down(t, (unsigned)off);
      if (lane < 64 - off) t = fmaxf(t, u);
    }
    float f = __shfl_down(t, 1u);        // exclusive suffix
    if (lane == 63) f = NINF;
    const float dr0 = -fmaxf(f, q0) - xf0;
    const float dr1 = -fmaxf(f, q1) - (xf0 + 1.f);
    const float dr2 = -fmaxf(f, q2) - (xf0 + 2.f);
    const float dr3 = -fmaxf(f, q3) - (xf0 + 3.f);

    // store only this block's 64 columns (lanes xt*16 .. xt*16+15)
    if ((lane >> 4) == xt) {
      const int cx = x0 - xt * 64;       // 0..60
      float v;
      v = fminf(dl0, dr0); g2s[y][cx + 0] = v * v;
      v = fminf(dl1, dr1); g2s[y][cx + 1] = v * v;
      v = fminf(dl2, dr2); g2s[y][cx + 2] = v * v;
      v = fminf(dl3, dr3); g2s[y][cx + 3] = v * v;
    }
  }

  __syncthreads();

  // ---------------- Phase B: col pass from LDS ----------------
  const int xin = tid & 63;
  const int ysub = tid >> 6;             // 0..7
  const int x = xt * 64 + xin;

  float local = 0.f;
#pragma unroll
  for (int g = 0; g < 8; ++g) {
    const int y0 = ysub * 32 + g * 4;

    float a0 = g2s[y0 + 0][xin];
    float a1 = g2s[y0 + 1][xin];
    float a2 = g2s[y0 + 2][xin];
    float a3 = g2s[y0 + 3][xin];

    const float U = fmaxf(fmaxf(a0, a1), fmaxf(a2, a3));
    const int r = (int)sqrtf(U) + 1;     // exact: (y-y')^2 >= U can't improve
    int lo = y0 - r; if (lo < 0) lo = 0;
    int hi = y0 + 3 + r; if (hi > H - 1) hi = H - 1;

    for (int yp = lo; yp <= hi; ++yp) {
      const float v = g2s[yp][xin];
      const float d0 = (float)(y0 - yp);
      const float d1 = d0 + 1.f;
      const float d2 = d0 + 2.f;
      const float d3 = d0 + 3.f;
      a0 = fminf(a0, fmaf(d0, d0, v));
      a1 = fminf(a1, fmaf(d1, d1, v));
      a2 = fminf(a2, fmaf(d2, d2, v));
      a3 = fminf(a3, fmaf(d3, d3, v));
    }

    // dt = sqrt(dt2), weighted by the OTHER mask (read from global inputs)
    if (m == 0) {
      const int* tg = target + (size_t)b * IMG + y0 * W + x;
      local += (float)tg[0 * W] * sqrtf(a0);
      local += (float)tg[1 * W] * sqrtf(a1);
      local += (float)tg[2 * W] * sqrtf(a2);
      local += (float)tg[3 * W] * sqrtf(a3);
    } else {
      const float* p = pred + (size_t)b * (2 * IMG) + y0 * W + x;
      local += ((p[0 * W + IMG] > p[0 * W]) ? 1.f : 0.f) * sqrtf(a0);
      local += ((p[1 * W + IMG] > p[1 * W]) ? 1.f : 0.f) * sqrtf(a1);
      local += ((p[2 * W + IMG] > p[2 * W]) ? 1.f : 0.f) * sqrtf(a2);
      local += ((p[3 * W + IMG] > p[3 * W]) ? 1.f : 0.f) * sqrtf(a3);
    }
  }

  red[tid] = local;
  __syncthreads();
  for (int s = 256; s > 0; s >>= 1) {
    if (tid < s) red[tid] += red[tid + s];
    __syncthreads();
  }
  if (tid == 0) partials[bi] = red[0];
}

// ---------------------------------------------------------------------------
__global__ __launch_bounds__(128) void finalize_kernel(
    const float* __restrict__ partials, float* __restrict__ out) {
  const int tid = threadIdx.x;
  __shared__ float red[128];
  red[tid] = partials[tid];
  __syncthreads();
  for (int k = 64; k > 0; k >>= 1) {
    if (tid < k) red[tid] += red[tid + k];
    __syncthreads();
  }
  if (tid == 0) out[0] = red[0] * (0.5f / (float)NPIX);
}

// ---------------------------------------------------------------------------
extern "C" void kernel_launch(void* const* d_in, const int* in_sizes, int n_in,
                              void* d_out, int out_size, void* d_ws, size_t ws_size,
                              hipStream_t stream) {
  const float* pred = (const float*)d_in[0];     // [16,2,256,256] f32
  const int* target = (const int*)d_in[1];       // [16,256,256] i32
  float* out = (float*)d_out;                    // scalar f32

  float* partials = (float*)d_ws;                // NBLK floats

  edt_fused_kernel<<<NBLK, 512, 0, stream>>>(pred, target, partials);
  finalize_kernel<<<1, 128, 0, stream>>>(partials, out);
}

// Round 9
// 78.425 us; speedup vs baseline: 3.5165x; 1.3138x over previous
//
#include <hip/hip_runtime.h>
#include <hip/hip_bf16.h>
#include <math.h>

// Hausdorff distance loss, exact EDT. Best-measured structure (R3):
// three small, fully-parallel kernels; no atomics; no grid sync.
// pred  [16, 2, 256, 256] f32 logits; target [16, 256, 256] i32 {0,1}.
// pred_lbl = (pred[:,1] > pred[:,0]); dt = exact 2D EDT of each mask.
// out = (sum(pred_lbl * dt(target)) + sum(target * dt(pred_lbl))) / (2*NPIX)
//
// Row pass: one wave per row, shuffle cummax scans (no LDS/barriers);
// stashes PRED labels only (target weights are read directly from target).
// Col pass: radius-bounded exact min-plus. Candidate y'=y gives upper bound
// U = g2[y,x]; any y' with (y-y')^2 >= U cannot win (g2 >= 0), so scanning
// [y0-r, y0+3+r] with r = floor(sqrt(U))+1 is exact for ANY input.
// Per-block partials; finalize tree-reduces 2048 partials.

#define B 16
#define H 256
#define W 256
#define IMG (H * W)            // 65536
#define NPIX (B * IMG)         // 1048576
#define NEGF (-1.0e6f)
#define NINF (-3.0e38f)
#define NBLK 2048              // colpass grid

// ---------------------------------------------------------------------------
// Kernel 1: row pass. One wave (64 lanes) per (m, b, y) row; lane owns x=4l..4l+3.
__global__ __launch_bounds__(256) void rowpass_kernel(
    const float* __restrict__ pred, const int* __restrict__ target,
    float* __restrict__ g2, unsigned char* __restrict__ plbl) {
  const int lane = threadIdx.x & 63;
  const int wid = threadIdx.x >> 6;
  const int row = blockIdx.x * 4 + wid;   // [0, 2*B*H)
  const int m = row >> 12;                // 0: pred mask, 1: target mask
  const int bh = row & 4095;
  const int b = bh >> 8;
  const int y = bh & 255;
  const int x0 = lane * 4;

  bool fg[4];
  if (m == 0) {
    const float* base = pred + (size_t)b * (2 * IMG) + y * W + x0;
    const float4 c0 = *(const float4*)(base);
    const float4 c1 = *(const float4*)(base + IMG);
    fg[0] = c1.x > c0.x; fg[1] = c1.y > c0.y;
    fg[2] = c1.z > c0.z; fg[3] = c1.w > c0.w;
    // stash pred labels for the m=1 colpass epilogue
    uchar4 lb;
    lb.x = fg[0]; lb.y = fg[1]; lb.z = fg[2]; lb.w = fg[3];
    *(uchar4*)(plbl + (size_t)b * IMG + y * W + x0) = lb;
  } else {
    const int4 tv = *(const int4*)(target + (size_t)b * IMG + y * W + x0);
    fg[0] = tv.x == 1; fg[1] = tv.y == 1; fg[2] = tv.z == 1; fg[3] = tv.w == 1;
  }

  const float xf0 = (float)x0;

  // ---- left-to-right inclusive cummax of pos_l = fg ? x : NEG
  float p0 = fg[0] ? xf0 : NEGF;
  float p1 = fmaxf(p0, fg[1] ? xf0 + 1.f : NEGF);
  float p2 = fmaxf(p1, fg[2] ? xf0 + 2.f : NEGF);
  float p3 = fmaxf(p2, fg[3] ? xf0 + 3.f : NEGF);
  float s = p3;
#pragma unroll
  for (int off = 1; off < 64; off <<= 1) {
    float u = __shfl_up(s, (unsigned)off);
    if (lane >= off) s = fmaxf(s, u);
  }
  float e = __shfl_up(s, 1u);              // exclusive prefix
  if (lane == 0) e = NINF;
  const float dl0 = xf0 - fmaxf(e, p0);
  const float dl1 = xf0 + 1.f - fmaxf(e, p1);
  const float dl2 = xf0 + 2.f - fmaxf(e, p2);
  const float dl3 = xf0 + 3.f - fmaxf(e, p3);

  // ---- right-to-left inclusive cummax of pos_r = fg ? -x : NEG
  float q3 = fg[3] ? -(xf0 + 3.f) : NEGF;
  float q2 = fmaxf(q3, fg[2] ? -(xf0 + 2.f) : NEGF);
  float q1 = fmaxf(q2, fg[1] ? -(xf0 + 1.f) : NEGF);
  float q0 = fmaxf(q1, fg[0] ? -xf0 : NEGF);
  float t = q0;
#pragma unroll
  for (int off = 1; off < 64; off <<= 1) {
    float u = __shfl_down(t, (unsigned)off);
    if (lane < 64 - off) t = fmaxf(t, u);
  }
  float f = __shfl_down(t, 1u);            // exclusive suffix
  if (lane == 63) f = NINF;
  const float dr0 = -fmaxf(f, q0) - xf0;
  const float dr1 = -fmaxf(f, q1) - (xf0 + 1.f);
  const float dr2 = -fmaxf(f, q2) - (xf0 + 2.f);
  const float dr3 = -fmaxf(f, q3) - (xf0 + 3.f);

  float4 o;
  float v;
  v = fminf(dl0, dr0); o.x = v * v;
  v = fminf(dl1, dr1); o.y = v * v;
  v = fminf(dl2, dr2); o.z = v * v;
  v = fminf(dl3, dr3); o.w = v * v;
  *(float4*)(g2 + (size_t)m * NPIX + (size_t)b * IMG + y * W + x0) = o;
}

// ---------------------------------------------------------------------------
// Kernel 2: radius-bounded column min-plus + fused weighted partial sums.
// Block = 256 thr handles 64 cols x 16 rows; thread owns 4 consecutive y.
// Writes ONE partial per block (no atomics).
__global__ __launch_bounds__(256) void colpass_kernel(
    const float* __restrict__ g2, const unsigned char* __restrict__ plbl,
    const int* __restrict__ target, float* __restrict__ partials) {
  const int tid = threadIdx.x;
  const int bi = blockIdx.x;           // [0, NBLK)
  const int xt = bi & 3;
  const int yt = (bi >> 2) & 15;
  const int m = (bi >> 6) & 1;
  const int b = bi >> 7;
  const int xin = tid & 63;
  const int ysub = tid >> 6;           // 0..3
  const int x = xt * 64 + xin;
  const int y0 = yt * 16 + ysub * 4;

  const float* __restrict__ gimg = g2 + (size_t)m * NPIX + (size_t)b * IMG;

  float a0 = gimg[(y0 + 0) * W + x];
  float a1 = gimg[(y0 + 1) * W + x];
  float a2 = gimg[(y0 + 2) * W + x];
  float a3 = gimg[(y0 + 3) * W + x];

  const float U = fmaxf(fmaxf(a0, a1), fmaxf(a2, a3));
  const int r = (int)sqrtf(U) + 1;     // exact: (y-y')^2 >= U can't improve
  int lo = y0 - r; if (lo < 0) lo = 0;
  int hi = y0 + 3 + r; if (hi > H - 1) hi = H - 1;

  for (int yp = lo; yp <= hi; ++yp) {
    const float v = gimg[yp * W + x];
    const float d0 = (float)(y0 - yp);
    const float d1 = d0 + 1.f;
    const float d2 = d0 + 2.f;
    const float d3 = d0 + 3.f;
    a0 = fminf(a0, fmaf(d0, d0, v));
    a1 = fminf(a1, fmaf(d1, d1, v));
    a2 = fminf(a2, fmaf(d2, d2, v));
    a3 = fminf(a3, fmaf(d3, d3, v));
  }

  // epilogue: dt = sqrt(dt2), weighted by the OTHER mask
  float local = 0.f;
  if (m == 0) {
    // dt of pred mask, weighted by target (read directly)
    const int* tg = target + (size_t)b * IMG + y0 * W + x;
    local += (float)tg[0 * W] * sqrtf(a0);
    local += (float)tg[1 * W] * sqrtf(a1);
    local += (float)tg[2 * W] * sqrtf(a2);
    local += (float)tg[3 * W] * sqrtf(a3);
  } else {
    // dt of target mask, weighted by pred labels (staged)
    const unsigned char* wl = plbl + (size_t)b * IMG + y0 * W + x;
    local += (float)wl[0 * W] * sqrtf(a0);
    local += (float)wl[1 * W] * sqrtf(a1);
    local += (float)wl[2 * W] * sqrtf(a2);
    local += (float)wl[3 * W] * sqrtf(a3);
  }

  __shared__ float red[256];
  red[tid] = local;
  __syncthreads();
  for (int s = 128; s > 0; s >>= 1) {
    if (tid < s) red[tid] += red[tid + s];
    __syncthreads();
  }
  if (tid == 0) partials[bi] = red[0];
}

// ---------------------------------------------------------------------------
// Kernel 3: reduce NBLK partials -> scalar. One block, deterministic.
__global__ __launch_bounds__(256) void finalize_kernel(
    const float* __restrict__ partials, float* __restrict__ out) {
  const int tid = threadIdx.x;
  float s = 0.f;
#pragma unroll
  for (int i = 0; i < NBLK / 256; ++i) s += partials[i * 256 + tid];
  __shared__ float red[256];
  red[tid] = s;
  __syncthreads();
  for (int k = 128; k > 0; k >>= 1) {
    if (tid < k) red[tid] += red[tid + k];
    __syncthreads();
  }
  if (tid == 0) out[0] = red[0] * (0.5f / (float)NPIX);
}

// ---------------------------------------------------------------------------
extern "C" void kernel_launch(void* const* d_in, const int* in_sizes, int n_in,
                              void* d_out, int out_size, void* d_ws, size_t ws_size,
                              hipStream_t stream) {
  const float* pred = (const float*)d_in[0];     // [16,2,256,256] f32
  const int* target = (const int*)d_in[1];       // [16,256,256] i32
  float* out = (float*)d_out;                    // scalar f32

  float* g2 = (float*)d_ws;                                 // 8 MB
  float* partials = g2 + 2 * (size_t)NPIX;                  // NBLK floats
  unsigned char* plbl = (unsigned char*)(partials + NBLK);  // 1 MB

  rowpass_kernel<<<2 * B * H / 4, 256, 0, stream>>>(pred, target, g2, plbl);
  colpass_kernel<<<NBLK, 256, 0, stream>>>(g2, plbl, target, partials);
  finalize_kernel<<<1, 256, 0, stream>>>(partials, out);
}